// Round 7
// baseline (1619.797 us; speedup 1.0000x reference)
//
#include <hip/hip_runtime.h>

#define N_NODES 100000
#define N_FEAT  512
#define HIDDEN  16
#define OUT_DIM 64
#define NNZ     3200000

// ---------------------------------------------------------------------------
// Kernel A: t1 = x @ W1   ([N,512] x [512,16] -> [N,16])
// block = 256 threads = 64 rows x 4 col-groups (4 cols each). W1 in LDS.
// x read as float4; 4 threads share a row -> 64B-line reuse via L1.
// Memory-bound: 204.8 MB of x at ~6.3 TB/s -> ~35 us floor.
// ---------------------------------------------------------------------------
__global__ __launch_bounds__(256) void gcn_gemm_xw1(
    const float* __restrict__ x, const float* __restrict__ W1,
    float* __restrict__ t1) {
  __shared__ float w1s[N_FEAT * HIDDEN];  // 32 KB
  {
    const float4* src = (const float4*)W1;
    float4* dst = (float4*)w1s;
    for (int i = threadIdx.x; i < N_FEAT * HIDDEN / 4; i += 256) dst[i] = src[i];
  }
  __syncthreads();

  int row = blockIdx.x * 64 + (threadIdx.x >> 2);
  int cq  = threadIdx.x & 3;  // col-group: cols [cq*4, cq*4+4)
  if (row >= N_NODES) return;

  const float4* xr  = (const float4*)(x + (size_t)row * N_FEAT);
  const float4* ws4 = (const float4*)w1s;   // float4 index = k*4 + cq

  float4 acc = make_float4(0.f, 0.f, 0.f, 0.f);
#pragma unroll 4
  for (int k4 = 0; k4 < N_FEAT / 4; ++k4) {
    float4 xv = xr[k4];
    float xk[4] = {xv.x, xv.y, xv.z, xv.w};
    int kb = k4 * 4;
#pragma unroll
    for (int j = 0; j < 4; ++j) {
      float4 w = ws4[(kb + j) * 4 + cq];
      acc.x = fmaf(xk[j], w.x, acc.x);
      acc.y = fmaf(xk[j], w.y, acc.y);
      acc.z = fmaf(xk[j], w.z, acc.z);
      acc.w = fmaf(xk[j], w.w, acc.w);
    }
  }
  *(float4*)&t1[(size_t)row * HIDDEN + cq * 4] = acc;
}

// ---------------------------------------------------------------------------
// Kernel B: SpMM (D=16) via atomics.  out[row, c] += val * f(src[col, c])
// LAYER2 fuses f(s) = relu(s + b1[c]) on the gather side (exact: elementwise,
// and spmm(L,h)@W2 == spmm(L, h@W2) by associativity keeps D=16 both layers).
// 4 consecutive threads = one edge; each thread owns a float4 c-group ->
// per edge: 12 edge-stream loads + 4 float4 gathers + 16 scalar atomics
// (32 VMEM instrs vs 80 for the 16-thread/edge mapping).
// unsafeAtomicAdd forces HW global_atomic_add_f32 (no CAS loop).
// ---------------------------------------------------------------------------
template <bool LAYER2>
__global__ __launch_bounds__(256) void gcn_spmm_atomic(
    const int* __restrict__ rows, const int* __restrict__ cols,
    const float* __restrict__ vals, const float* __restrict__ src,
    const float* __restrict__ b1, float* __restrict__ out) {
  int t = blockIdx.x * 256 + threadIdx.x;
  int cg = t & 3;  // float4 col-group: cols [cg*4, cg*4+4)
  float4 b1v = make_float4(0.f, 0.f, 0.f, 0.f);
  if (LAYER2) b1v = ((const float4*)b1)[cg];
  int estride = (gridDim.x * 256) >> 2;
  for (int e = t >> 2; e < NNZ; e += estride) {
    int col = cols[e];
    int row = rows[e];
    float v = vals[e];
    float4 s = *(const float4*)(src + col * HIDDEN + cg * 4);
    if (LAYER2) {
      s.x = fmaxf(s.x + b1v.x, 0.f);
      s.y = fmaxf(s.y + b1v.y, 0.f);
      s.z = fmaxf(s.z + b1v.z, 0.f);
      s.w = fmaxf(s.w + b1v.w, 0.f);
    }
    float* dst = out + row * HIDDEN + cg * 4;
    unsafeAtomicAdd(dst + 0, v * s.x);
    unsafeAtomicAdd(dst + 1, v * s.y);
    unsafeAtomicAdd(dst + 2, v * s.z);
    unsafeAtomicAdd(dst + 3, v * s.w);
  }
}

// ---------------------------------------------------------------------------
// Kernel C: out = sigmoid(t2 @ W2 + b2)   ([N,16] x [16,64] -> [N,64])
// thread per (row, c); W2 in LDS; t2 row loads are wave-broadcast
// (one wave == one row: all 64 lanes read the same 16 t2 values).
// ---------------------------------------------------------------------------
__global__ __launch_bounds__(256) void gcn_gemm_w2_sigmoid(
    const float* __restrict__ t2, const float* __restrict__ W2,
    const float* __restrict__ b2, float* __restrict__ out) {
  __shared__ float w2s[HIDDEN * OUT_DIM];  // 4 KB
  for (int i = threadIdx.x; i < HIDDEN * OUT_DIM; i += 256) w2s[i] = W2[i];
  __syncthreads();

  int idx = blockIdx.x * 256 + threadIdx.x;
  if (idx >= N_NODES * OUT_DIM) return;
  int row = idx >> 6;
  int c   = idx & 63;

  const float* tr = t2 + (size_t)row * HIDDEN;
  float acc = b2[c];
#pragma unroll
  for (int k = 0; k < HIDDEN; ++k) acc = fmaf(tr[k], w2s[k * OUT_DIM + c], acc);

  out[idx] = 1.f / (1.f + __expf(-acc));
}

// ---------------------------------------------------------------------------
extern "C" void kernel_launch(void* const* d_in, const int* in_sizes, int n_in,
                              void* d_out, int out_size, void* d_ws,
                              size_t ws_size, hipStream_t stream) {
  const float* x        = (const float*)d_in[0];
  const int*   lap_rows = (const int*)d_in[1];
  const int*   lap_cols = (const int*)d_in[2];
  const float* lap_vals = (const float*)d_in[3];
  const float* W1       = (const float*)d_in[4];
  const float* b1       = (const float*)d_in[5];
  const float* W2       = (const float*)d_in[6];
  const float* b2       = (const float*)d_in[7];
  float* out = (float*)d_out;

  const size_t seg = (size_t)N_NODES * HIDDEN;          // 1.6M floats
  const size_t seg_bytes = seg * sizeof(float);         // 6.4 MB

  // Scratch layout. Primary: all three temporaries in d_ws (19.2 MB),
  // h_acc|t2 contiguous -> one memset. Defensive fallback (ws_size <
  // 19.2 MB): t1/h_acc live in d_out (both dead before the final kernel
  // overwrites d_out), only t2 (6.4 MB) in ws.
  float *t1, *h_acc, *t2;
  if (ws_size >= 3 * seg_bytes) {
    t1    = (float*)d_ws;
    h_acc = t1 + seg;
    t2    = h_acc + seg;
    hipMemsetAsync(h_acc, 0, 2 * seg_bytes, stream);
  } else {
    t1    = out;              // d_out[0 .. 1.6M floats)
    h_acc = out + seg;        // d_out[1.6M .. 3.2M floats)
    t2    = (float*)d_ws;     // needs only 6.4 MB of ws
    hipMemsetAsync(h_acc, 0, seg_bytes, stream);
    hipMemsetAsync(t2, 0, seg_bytes, stream);
  }

  // t1 = x @ W1
  gcn_gemm_xw1<<<(N_NODES + 63) / 64, 256, 0, stream>>>(x, W1, t1);
  // h_acc = spmm(L, t1)
  gcn_spmm_atomic<false><<<2048, 256, 0, stream>>>(lap_rows, lap_cols, lap_vals,
                                                   t1, nullptr, h_acc);
  // t2 = spmm(L, relu(h_acc + b1))
  gcn_spmm_atomic<true><<<2048, 256, 0, stream>>>(lap_rows, lap_cols, lap_vals,
                                                  h_acc, b1, t2);
  // out = sigmoid(t2 @ W2 + b2)  (reads t2, writes whole d_out; disjoint)
  gcn_gemm_w2_sigmoid<<<(N_NODES * OUT_DIM + 255) / 256, 256, 0, stream>>>(
      t2, W2, b2, out);
}